// Round 1
// baseline (1438.110 us; speedup 1.0000x reference)
//
#include <hip/hip_runtime.h>
#include <math.h>

#define C_IN   64
#define T_DIM  256
#define V_DIM  25
#define C_OUT  256
#define S_DIM  3
#define BN_EPS 1e-5f

#define SC       (S_DIM * C_IN)          // 192
#define TW       (T_DIM * V_DIM)         // 6400
#define AP_PER_N (S_DIM * V_DIM * V_DIM) // 1875

// ---------------------------------------------------------------------------
// Kernel 1: A_personalized = tanh(A_pers[:n])  -> out;  A_final = A + tanh -> ws
// ---------------------------------------------------------------------------
__global__ void k_prep_a(const float* __restrict__ A, const float* __restrict__ A_pers,
                         float* __restrict__ out_ap, float* __restrict__ af, int total) {
    int i = blockIdx.x * 256 + threadIdx.x;
    if (i < total) {
        float t = tanhf(A_pers[i]);
        out_ap[i] = t;
        af[i] = A[i % AP_PER_N] + t;
    }
}

// ---------------------------------------------------------------------------
// Kernel 2: transpose conv_w (S,C_OUT,C_IN) -> wt4[sc][ob][k] with o = ob + 64k
//           so stage-2 lane ob reads one float4 per K-iter.
// ---------------------------------------------------------------------------
__global__ void k_prep_w(const float* __restrict__ conv_w, float* __restrict__ wt4) {
    int j = blockIdx.x * 256 + threadIdx.x;    // SC*C_OUT = 49152
    if (j < SC * C_OUT) {
        int sc = j >> 8;
        int r  = j & 255;
        int ob = r >> 2, k = r & 3;
        int o  = ob + 64 * k;
        int s  = sc >> 6, c = sc & 63;
        wt4[j] = conv_w[(s * C_OUT + o) * C_IN + c];
    }
}

// ---------------------------------------------------------------------------
// Main kernel: per block = (t-pair, n). Computes y_pre for 256 channels x 2 t x 25 w,
// writes to y region of d_out, accumulates per-channel sum/sumsq.
// ---------------------------------------------------------------------------
__global__ __launch_bounds__(256) void k_main(const float* __restrict__ x,
                                              const float* __restrict__ af,
                                              const float* __restrict__ wt4f,
                                              float* __restrict__ y,
                                              float* __restrict__ sums) {
    __shared__ __align__(16) float sAf[AP_PER_N];  // 1875 floats
    __shared__ __align__(16) float sX[C_IN * 50];  // 3200 floats (c, t-pair*25+v)
    __shared__ __align__(16) float sXa[SC * 56];   // [sc][t*28 + w], pad 25->28
    __shared__ float sSum[C_OUT];
    __shared__ float sSqs[C_OUT];

    const int tid  = threadIdx.x;
    const int nIdx = blockIdx.y;
    const int t0   = blockIdx.x * 2;

    for (int i = tid; i < AP_PER_N; i += 256) sAf[i] = af[nIdx * AP_PER_N + i];
    {
        const float* xb = x + (size_t)nIdx * C_IN * TW + (size_t)t0 * V_DIM;
        for (int i = tid; i < C_IN * 50; i += 256) {
            int c = i / 50, r = i % 50;
            sX[i] = xb[(size_t)c * TW + r];
        }
    }
    sSum[tid] = 0.f;
    sSqs[tid] = 0.f;
    __syncthreads();

    // ---- stage 1: xa[sc][t][w] = sum_v x[c][t][v] * Af[s][v][w] ----
    for (int sid = tid; sid < SC * 2; sid += 256) {
        int sc = sid >> 1, t = sid & 1;
        int s = sc >> 6, c = sc & 63;
        const float* afp = sAf + s * (V_DIM * V_DIM);
        float accw[V_DIM];
#pragma unroll
        for (int w = 0; w < V_DIM; ++w) accw[w] = 0.f;
        for (int v = 0; v < V_DIM; ++v) {
            float xvv = sX[c * 50 + t * V_DIM + v];
            const float* rp = afp + v * V_DIM;
#pragma unroll
            for (int w = 0; w < V_DIM; ++w) accw[w] = fmaf(xvv, rp[w], accw[w]);
        }
        float* xap = sXa + sc * 56 + t * 28;
#pragma unroll
        for (int w = 0; w < V_DIM; ++w) xap[w] = accw[w];
    }
    __syncthreads();

    // ---- stage 2: y[o][t][w] = sum_sc wt[sc][o] * xa[sc][t][w] ----
    // lane = ob (64), wave: part = (wq<<1)|t ; thread owns o = ob+64k, k=0..3,
    // w in [w0, w0+13) with w0 = wq*12 (w=12 computed by both halves, owned by wq=1)
    const int ob   = tid & 63;
    const int part = tid >> 6;
    const int t    = part & 1;
    const int wq   = part >> 1;
    const int w0   = wq * 12;

    float acc[4][13];
#pragma unroll
    for (int k = 0; k < 4; ++k)
#pragma unroll
        for (int j = 0; j < 13; ++j) acc[k][j] = 0.f;

    const float4* wt4 = (const float4*)wt4f;
#pragma unroll 2
    for (int sc = 0; sc < SC; ++sc) {
        float4 wv = wt4[sc * 64 + ob];
        const float* xr = sXa + sc * 56 + t * 28 + w0;
        float4 xa0 = *(const float4*)(xr);
        float4 xa1 = *(const float4*)(xr + 4);
        float4 xa2 = *(const float4*)(xr + 8);
        float  xaS = xr[12];
        float xav[13] = {xa0.x, xa0.y, xa0.z, xa0.w,
                         xa1.x, xa1.y, xa1.z, xa1.w,
                         xa2.x, xa2.y, xa2.z, xa2.w, xaS};
#pragma unroll
        for (int j = 0; j < 13; ++j) {
            acc[0][j] = fmaf(wv.x, xav[j], acc[0][j]);
            acc[1][j] = fmaf(wv.y, xav[j], acc[1][j]);
            acc[2][j] = fmaf(wv.z, xav[j], acc[2][j]);
            acc[3][j] = fmaf(wv.w, xav[j], acc[3][j]);
        }
    }

    // ---- epilogue: write y_pre, accumulate channel sums ----
    const size_t ybase = (size_t)nIdx * C_OUT * TW + (size_t)(t0 + t) * V_DIM + w0;
#pragma unroll
    for (int k = 0; k < 4; ++k) {
        int o = ob + 64 * k;
        float s1 = 0.f, s2 = 0.f;
        float* yp = y + ybase + (size_t)o * TW;
#pragma unroll
        for (int j = 0; j < 13; ++j) {
            if ((wq == 1) || (j < 12)) {
                float v = acc[k][j];
                yp[j] = v;
                s1 += v;
                s2 += v * v;
            }
        }
        atomicAdd(&sSum[o], s1);
        atomicAdd(&sSqs[o], s2);
    }
    __syncthreads();
    atomicAdd(&sums[tid], sSum[tid]);
    atomicAdd(&sums[C_OUT + tid], sSqs[tid]);
}

// ---------------------------------------------------------------------------
// Stats: per-channel mean/var -> scale/shift
// ---------------------------------------------------------------------------
__global__ void k_stats(const float* __restrict__ sums, const float* __restrict__ bn_w,
                        const float* __restrict__ bn_b, float* __restrict__ ss, int n) {
    int o = threadIdx.x;
    float cnt   = (float)n * (float)TW;
    float mean  = sums[o] / cnt;
    float var   = sums[C_OUT + o] / cnt - mean * mean;
    float scale = bn_w[o] * rsqrtf(var + BN_EPS);
    ss[o]         = scale;
    ss[C_OUT + o] = bn_b[o] - mean * scale;
}

// ---------------------------------------------------------------------------
// Finalize: y = relu(y * scale[o] + shift[o]) in place, float4
// ---------------------------------------------------------------------------
__global__ __launch_bounds__(256) void k_final(float* __restrict__ y,
                                               const float* __restrict__ ss,
                                               unsigned total4) {
    unsigned stride = gridDim.x * 256u;
    for (unsigned i = blockIdx.x * 256u + threadIdx.x; i < total4; i += stride) {
        float4 v = ((float4*)y)[i];
        unsigned o = (i / 1600u) & 255u;   // 1600 float4 per (n,o) slab
        float sc = ss[o], sh = ss[C_OUT + o];
        v.x = fmaxf(fmaf(v.x, sc, sh), 0.f);
        v.y = fmaxf(fmaf(v.y, sc, sh), 0.f);
        v.z = fmaxf(fmaf(v.z, sc, sh), 0.f);
        v.w = fmaxf(fmaf(v.w, sc, sh), 0.f);
        ((float4*)y)[i] = v;
    }
}

// ---------------------------------------------------------------------------
extern "C" void kernel_launch(void* const* d_in, const int* in_sizes, int n_in,
                              void* d_out, int out_size, void* d_ws, size_t ws_size,
                              hipStream_t stream) {
    const float* x      = (const float*)d_in[0];
    const float* A      = (const float*)d_in[1];
    const float* A_pers = (const float*)d_in[2];
    const float* conv_w = (const float*)d_in[3];
    // d_in[4] = conv_b: cancels under training-mode BatchNorm -> unused
    const float* bn_w   = (const float*)d_in[5];
    const float* bn_b   = (const float*)d_in[6];

    const int n = in_sizes[0] / (C_IN * TW);   // 64

    float* out_ap = (float*)d_out;
    float* y      = (float*)d_out + (size_t)n * AP_PER_N;

    float* ws   = (float*)d_ws;
    float* sums = ws;                       // 2*C_OUT floats
    float* ss   = ws + 2 * C_OUT;           // 2*C_OUT floats
    float* af   = ws + 4 * C_OUT;           // n*AP_PER_N floats
    float* wt4  = af + (size_t)n * AP_PER_N; // SC*C_OUT floats (16B aligned: (1024+120000)*4 % 16 == 0)

    hipMemsetAsync(sums, 0, 2 * C_OUT * sizeof(float), stream);

    int totA = n * AP_PER_N;
    k_prep_a<<<(totA + 255) / 256, 256, 0, stream>>>(A, A_pers, out_ap, af, totA);
    k_prep_w<<<(SC * C_OUT + 255) / 256, 256, 0, stream>>>(conv_w, wt4);
    k_main<<<dim3(T_DIM / 2, n), 256, 0, stream>>>(x, af, wt4, y, sums);
    k_stats<<<1, 256, 0, stream>>>(sums, bn_w, bn_b, ss, n);
    k_final<<<4096, 256, 0, stream>>>(y, ss, (unsigned)((size_t)n * C_OUT * TW / 4));
}

// Round 2
// 641.805 us; speedup vs baseline: 2.2407x; 2.2407x over previous
//
#include <hip/hip_runtime.h>
#include <math.h>

#define C_IN   64
#define T_DIM  256
#define V_DIM  25
#define C_OUT  256
#define S_DIM  3
#define BN_EPS 1e-5f

#define SC       (S_DIM * C_IN)          // 192
#define TW       (T_DIM * V_DIM)         // 6400
#define AP_PER_N (S_DIM * V_DIM * V_DIM) // 1875
#define LDB      200                     // sXa row stride (bf16), 400B: 16B-aligned, bank-friendly

typedef __attribute__((ext_vector_type(8))) short bf16x8;
typedef __attribute__((ext_vector_type(4))) float f32x4;

__device__ __forceinline__ unsigned short f2bf(float f) {
    unsigned u = __builtin_bit_cast(unsigned, f);
    unsigned r = u + 0x7fffu + ((u >> 16) & 1u);
    return (unsigned short)(r >> 16);
}

// ---------------------------------------------------------------------------
// Kernel 1: A_personalized = tanh(A_pers[:n]) -> out;  A_final = A + tanh -> ws
// ---------------------------------------------------------------------------
__global__ void k_prep_a(const float* __restrict__ A, const float* __restrict__ A_pers,
                         float* __restrict__ out_ap, float* __restrict__ af, int total) {
    int i = blockIdx.x * 256 + threadIdx.x;
    if (i < total) {
        float t = tanhf(A_pers[i]);
        out_ap[i] = t;
        af[i] = A[i % AP_PER_N] + t;
    }
}

// ---------------------------------------------------------------------------
// Kernel 2: conv_w (S,C_OUT,C_IN) -> bf16 wt_b[o][sc], sc = s*64+c (A-frag layout)
// ---------------------------------------------------------------------------
__global__ void k_prep_w(const float* __restrict__ conv_w, unsigned short* __restrict__ wt_b) {
    int j = blockIdx.x * 256 + threadIdx.x;    // C_OUT*SC = 49152
    if (j < C_OUT * SC) {
        int o  = j / SC;
        int sc = j - o * SC;
        int s  = sc >> 6, c = sc & 63;
        wt_b[j] = f2bf(conv_w[(s * C_OUT + o) * C_IN + c]);
    }
}

// ---------------------------------------------------------------------------
// Main kernel: block = (t-pair, n). Stage 1: xa -> LDS bf16 [tw][sc].
// Stage 2: MFMA GEMM  y[o][tw] = sum_sc wt[o][sc] * xa[sc][tw]  (M=256,K=192,N=64pad)
// ---------------------------------------------------------------------------
__global__ __launch_bounds__(256, 2) void k_main(const float* __restrict__ x,
                                                 const float* __restrict__ af,
                                                 const unsigned short* __restrict__ wt_b,
                                                 float* __restrict__ y,
                                                 float* __restrict__ sums) {
    __shared__ __align__(16) float sAf[AP_PER_N];          // 7.5 KB
    __shared__ __align__(16) float sX[C_IN * 50];          // 12.8 KB
    __shared__ __align__(16) unsigned short sXa[64 * LDB]; // 25.6 KB  [tw][sc]
    __shared__ float sSum[C_OUT];
    __shared__ float sSqs[C_OUT];

    const int tid  = threadIdx.x;
    const int nIdx = blockIdx.y;
    const int t0   = blockIdx.x * 2;

    const int lane  = tid & 63;
    const int wv    = tid >> 6;        // wave 0..3
    const int wbase = wv * 64;         // o-tile base
    const int arow  = lane & 15;
    const int kgrp  = lane >> 4;       // 0..3
    const int koff  = kgrp * 8;

    // A-fragments (weights) -> registers; issue early, latency hides under stage 1
    bf16x8 afrag[4][6];
#pragma unroll
    for (int m = 0; m < 4; ++m)
#pragma unroll
        for (int ks = 0; ks < 6; ++ks)
            afrag[m][ks] = *(const bf16x8*)(wt_b + (size_t)(wbase + m * 16 + arow) * SC + ks * 32 + koff);

    // stage LDS inputs
    for (int i = tid; i < AP_PER_N; i += 256) sAf[i] = af[nIdx * AP_PER_N + i];
    {
        const float* xb = x + (size_t)nIdx * C_IN * TW + (size_t)t0 * V_DIM;
        for (int i = tid; i < C_IN * 50; i += 256) {
            int c = i / 50, r = i - c * 50;
            sX[i] = xb[(size_t)c * TW + r];
        }
    }
    // zero padding rows tw = 50..63 of sXa
    for (int i = tid; i < 14 * LDB; i += 256) sXa[50 * LDB + i] = 0;
    sSum[tid] = 0.f;
    sSqs[tid] = 0.f;
    __syncthreads();

    // ---- stage 1: xa[tw][sc] = sum_v x[c][t][v] * Af[s][v][w]  (fp32 -> bf16 LDS) ----
    // 768 balanced tasks: task = sc*4 + t*2 + wh ; each computes 13 w values
#pragma unroll
    for (int it = 0; it < 3; ++it) {
        int task = tid + it * 256;
        int sc = task >> 2;
        int t  = (task >> 1) & 1;
        int w0 = (task & 1) * 12;
        int s  = sc >> 6, c = sc & 63;
        const float* afp = sAf + s * 625 + w0;
        const float* xp  = sX + c * 50 + t * 25;
        float accw[13];
#pragma unroll
        for (int j = 0; j < 13; ++j) accw[j] = 0.f;
        for (int v = 0; v < V_DIM; ++v) {
            float xv = xp[v];
            const float* rp = afp + v * 25;
#pragma unroll
            for (int j = 0; j < 13; ++j) accw[j] = fmaf(xv, rp[j], accw[j]);
        }
        unsigned short* xap = sXa + (t * 25 + w0) * LDB + sc;
#pragma unroll
        for (int j = 0; j < 13; ++j) xap[j * LDB] = f2bf(accw[j]);
    }
    __syncthreads();

    // ---- stage 2: MFMA ----
    f32x4 acc[4][4];
#pragma unroll
    for (int m = 0; m < 4; ++m)
#pragma unroll
        for (int nn = 0; nn < 4; ++nn) acc[m][nn] = (f32x4){0.f, 0.f, 0.f, 0.f};

#pragma unroll
    for (int ks = 0; ks < 6; ++ks) {
        bf16x8 bfrag[4];
#pragma unroll
        for (int nn = 0; nn < 4; ++nn)
            bfrag[nn] = *(const bf16x8*)(&sXa[(nn * 16 + arow) * LDB + ks * 32 + koff]);
#pragma unroll
        for (int m = 0; m < 4; ++m)
#pragma unroll
            for (int nn = 0; nn < 4; ++nn)
                acc[m][nn] = __builtin_amdgcn_mfma_f32_16x16x32_bf16(afrag[m][ks], bfrag[nn], acc[m][nn], 0, 0, 0);
    }

    // ---- epilogue: write y_pre, channel sums ----
    const size_t ybase = (size_t)nIdx * C_OUT * TW + (size_t)t0 * V_DIM;
#pragma unroll
    for (int m = 0; m < 4; ++m) {
#pragma unroll
        for (int r = 0; r < 4; ++r) {
            const int o = wbase + m * 16 + (kgrp << 2) + r;
            float s1 = 0.f, s2 = 0.f;
            float* yp = y + ybase + (size_t)o * TW;
#pragma unroll
            for (int nn = 0; nn < 4; ++nn) {
                int tw = nn * 16 + arow;
                float v = acc[m][nn][r];
                if (tw < 50) {
                    yp[tw] = v;
                    s1 += v;
                    s2 += v * v;
                }
            }
#pragma unroll
            for (int off = 1; off < 16; off <<= 1) {
                s1 += __shfl_xor(s1, off, 64);
                s2 += __shfl_xor(s2, off, 64);
            }
            if (arow == 0) {
                atomicAdd(&sSum[o], s1);
                atomicAdd(&sSqs[o], s2);
            }
        }
    }
    __syncthreads();
    atomicAdd(&sums[tid], sSum[tid]);
    atomicAdd(&sums[C_OUT + tid], sSqs[tid]);
}

// ---------------------------------------------------------------------------
// Stats: per-channel mean/var -> scale/shift
// ---------------------------------------------------------------------------
__global__ void k_stats(const float* __restrict__ sums, const float* __restrict__ bn_w,
                        const float* __restrict__ bn_b, float* __restrict__ ss, int n) {
    int o = threadIdx.x;
    float cnt   = (float)n * (float)TW;
    float mean  = sums[o] / cnt;
    float var   = sums[C_OUT + o] / cnt - mean * mean;
    float scale = bn_w[o] * rsqrtf(var + BN_EPS);
    ss[o]         = scale;
    ss[C_OUT + o] = bn_b[o] - mean * scale;
}

// ---------------------------------------------------------------------------
// Finalize: y = relu(y * scale[o] + shift[o]) in place, float4
// ---------------------------------------------------------------------------
__global__ __launch_bounds__(256) void k_final(float* __restrict__ y,
                                               const float* __restrict__ ss,
                                               unsigned total4) {
    unsigned stride = gridDim.x * 256u;
    for (unsigned i = blockIdx.x * 256u + threadIdx.x; i < total4; i += stride) {
        float4 v = ((float4*)y)[i];
        unsigned o = (i / 1600u) & 255u;   // 1600 float4 per (n,o) slab
        float sc = ss[o], sh = ss[C_OUT + o];
        v.x = fmaxf(fmaf(v.x, sc, sh), 0.f);
        v.y = fmaxf(fmaf(v.y, sc, sh), 0.f);
        v.z = fmaxf(fmaf(v.z, sc, sh), 0.f);
        v.w = fmaxf(fmaf(v.w, sc, sh), 0.f);
        ((float4*)y)[i] = v;
    }
}

// ---------------------------------------------------------------------------
extern "C" void kernel_launch(void* const* d_in, const int* in_sizes, int n_in,
                              void* d_out, int out_size, void* d_ws, size_t ws_size,
                              hipStream_t stream) {
    const float* x      = (const float*)d_in[0];
    const float* A      = (const float*)d_in[1];
    const float* A_pers = (const float*)d_in[2];
    const float* conv_w = (const float*)d_in[3];
    // d_in[4] = conv_b: cancels under training-mode BatchNorm -> unused
    const float* bn_w   = (const float*)d_in[5];
    const float* bn_b   = (const float*)d_in[6];

    const int n = in_sizes[0] / (C_IN * TW);   // 64

    float* out_ap = (float*)d_out;
    float* y      = (float*)d_out + (size_t)n * AP_PER_N;

    float* ws   = (float*)d_ws;
    float* sums = ws;                         // 2*C_OUT floats
    float* ss   = ws + 2 * C_OUT;             // 2*C_OUT floats
    float* af   = ws + 4 * C_OUT;             // n*AP_PER_N floats
    unsigned short* wt_b = (unsigned short*)(af + (size_t)n * AP_PER_N); // C_OUT*SC bf16

    hipMemsetAsync(sums, 0, 2 * C_OUT * sizeof(float), stream);

    int totA = n * AP_PER_N;
    k_prep_a<<<(totA + 255) / 256, 256, 0, stream>>>(A, A_pers, out_ap, af, totA);
    k_prep_w<<<(C_OUT * SC + 255) / 256, 256, 0, stream>>>(conv_w, wt_b);
    k_main<<<dim3(T_DIM / 2, n), 256, 0, stream>>>(x, af, wt_b, y, sums);
    k_stats<<<1, 256, 0, stream>>>(sums, bn_w, bn_b, ss, n);
    k_final<<<4096, 256, 0, stream>>>(y, ss, (unsigned)((size_t)n * C_OUT * TW / 4));
}

// Round 3
// 474.434 us; speedup vs baseline: 3.0312x; 1.3528x over previous
//
#include <hip/hip_runtime.h>
#include <math.h>

#define C_IN   64
#define T_DIM  256
#define V_DIM  25
#define C_OUT  256
#define S_DIM  3
#define BN_EPS 1e-5f

#define SC       (S_DIM * C_IN)          // 192
#define TW       (T_DIM * V_DIM)         // 6400
#define AP_PER_N (S_DIM * V_DIM * V_DIM) // 1875
#define LDB      200                     // sXa row stride (bf16): 400 B rows
#define LDX      40                      // sX row stride (bf16): 80 B rows
#define NR       32                      // atomic replica count

typedef __attribute__((ext_vector_type(8))) short bf16x8;
typedef __attribute__((ext_vector_type(4))) float f32x4;

__device__ __forceinline__ unsigned short f2bf(float f) {
    unsigned u = __builtin_bit_cast(unsigned, f);
    unsigned r = u + 0x7fffu + ((u >> 16) & 1u);
    return (unsigned short)(r >> 16);
}

// ---------------------------------------------------------------------------
// A_personalized = tanh(A_pers[:n]) -> output 0
// ---------------------------------------------------------------------------
__global__ void k_prep_a(const float* __restrict__ A_pers, float* __restrict__ out_ap,
                         int total) {
    int i = blockIdx.x * 256 + threadIdx.x;
    if (i < total) out_ap[i] = tanhf(A_pers[i]);
}

// ---------------------------------------------------------------------------
// Pack A_final = A + tanh(A_pers) into exact MFMA B-fragment layout (bf16):
// afb[n][s][nt][lane][i] = Af[v = (lane>>4)*8+i][w = nt*16 + (lane&15)], 0-pad
// ---------------------------------------------------------------------------
__global__ void k_prep_afb(const float* __restrict__ A, const float* __restrict__ A_pers,
                           unsigned short* __restrict__ afb, int total) {
    int j = blockIdx.x * 256 + threadIdx.x;
    if (j >= total) return;
    int i    = j & 7;
    int lane = (j >> 3) & 63;
    int nt   = (j >> 9) & 1;
    int sn   = j >> 10;          // n*3 + s
    int s    = sn % 3;
    int n    = sn / 3;
    int v    = ((lane >> 4) << 3) + i;
    int w    = nt * 16 + (lane & 15);
    float val = 0.f;
    if (v < V_DIM && w < V_DIM)
        val = A[(s * V_DIM + v) * V_DIM + w] +
              tanhf(A_pers[((n * S_DIM + s) * V_DIM + v) * V_DIM + w]);
    afb[j] = f2bf(val);
}

// ---------------------------------------------------------------------------
// conv_w (S,C_OUT,C_IN) -> bf16 wt_b[o][sc], sc = s*64+c (stage-2 A-frag rows)
// ---------------------------------------------------------------------------
__global__ void k_prep_w(const float* __restrict__ conv_w, unsigned short* __restrict__ wt_b) {
    int j = blockIdx.x * 256 + threadIdx.x;    // C_OUT*SC = 49152
    if (j < C_OUT * SC) {
        int o  = j / SC;
        int sc = j - o * SC;
        int s  = sc >> 6, c = sc & 63;
        wt_b[j] = f2bf(conv_w[(s * C_OUT + o) * C_IN + c]);
    }
}

// ---------------------------------------------------------------------------
// Main: block = (t-pair, n). Stage1 MFMA: xa = X·Af -> sXa[tw][sc] (bf16).
// Stage2 MFMA: y[o][tw] = wt[o][sc] · xa[sc][tw].
// PASS 0: channel sums only (replicated atomic bins). PASS 1: BN+ReLU fused y write.
// ---------------------------------------------------------------------------
template <int PASS>
__global__ __launch_bounds__(256, 4) void k_main(const float* __restrict__ x,
                                                 const unsigned short* __restrict__ afb,
                                                 const unsigned short* __restrict__ wt_b,
                                                 float* __restrict__ y,
                                                 float* __restrict__ bins,
                                                 const float2* __restrict__ ssv) {
    __shared__ __align__(16) unsigned short sX[128 * LDX];   // 10.24 KB  [ct row=2c+t][v pad 40]
    __shared__ __align__(16) unsigned short sXa[64 * LDB];   // 25.6 KB   [tw][sc pad 200]

    const int tid  = threadIdx.x;
    const int nIdx = blockIdx.y;
    const int t0   = blockIdx.x * 2;
    const int lane = tid & 63;
    const int wv   = tid >> 6;     // wave 0..3
    const int l15  = lane & 15;
    const int kg   = lane >> 4;    // 0..3

    // zero the K-pad columns v=25..31 of sX (read by kg=3 fragment)
    for (int j = tid; j < 128 * 7; j += 256) {
        int row = j / 7, rem = j - row * 7;
        sX[row * LDX + 25 + rem] = 0;
    }
    // stage x -> sX bf16 (coalesced 50-float row runs)
    {
        const float* xb = x + (size_t)nIdx * C_IN * TW + (size_t)t0 * V_DIM;
        for (int i = tid; i < C_IN * 50; i += 256) {
            int c = i / 50, r = i - c * 50;
            int t = r / 25, v = r - t * 25;
            sX[(2 * c + t) * LDX + v] = f2bf(xb[(size_t)c * TW + r]);
        }
    }
    __syncthreads();

    // ---- stage 1: 12 MFMA per wave ----
    {
        const unsigned short* afbN = afb + (size_t)nIdx * (6 * 64 * 8);
#pragma unroll
        for (int sq = 0; sq < 6; ++sq) {      // sq = s*2 + nt
            int s = sq >> 1, nt = sq & 1;
            bf16x8 bfragS = *(const bf16x8*)(afbN + (sq * 64 + lane) * 8);
#pragma unroll
            for (int m2 = 0; m2 < 2; ++m2) {
                int mt = wv * 2 + m2;
                bf16x8 afragX = *(const bf16x8*)(sX + (mt * 16 + l15) * LDX + kg * 8);
                f32x4 c4 = __builtin_amdgcn_mfma_f32_16x16x32_bf16(
                    afragX, bfragS, (f32x4){0.f, 0.f, 0.f, 0.f}, 0, 0, 0);
                int w = nt * 16 + l15;
                if (w < V_DIM) {
#pragma unroll
                    for (int r = 0; r < 4; ++r) {
                        int ctRow = mt * 16 + kg * 4 + r;
                        int c = ctRow >> 1, t = ctRow & 1;
                        sXa[(t * V_DIM + w) * LDB + s * 64 + c] = f2bf(c4[r]);
                    }
                }
            }
        }
    }
    __syncthreads();

    // ---- stage 2: M=256 (o), N=64 (tw, 50 valid), K=192 ----
    f32x4 acc[4][4];
#pragma unroll
    for (int m = 0; m < 4; ++m)
#pragma unroll
        for (int nn = 0; nn < 4; ++nn) acc[m][nn] = (f32x4){0.f, 0.f, 0.f, 0.f};

    const unsigned short* wrow = wt_b + (size_t)(wv * 64 + l15) * SC + kg * 8;
#pragma unroll 1
    for (int ks = 0; ks < 6; ++ks) {
        bf16x8 aF[4], bF[4];
#pragma unroll
        for (int m = 0; m < 4; ++m)
            aF[m] = *(const bf16x8*)(wrow + m * 16 * SC + ks * 32);
#pragma unroll
        for (int nn = 0; nn < 4; ++nn)
            bF[nn] = *(const bf16x8*)(sXa + (nn * 16 + l15) * LDB + ks * 32 + kg * 8);
#pragma unroll
        for (int m = 0; m < 4; ++m)
#pragma unroll
            for (int nn = 0; nn < 4; ++nn)
                acc[m][nn] = __builtin_amdgcn_mfma_f32_16x16x32_bf16(aF[m], bF[nn], acc[m][nn], 0, 0, 0);
    }

    const int wbase = wv * 64;
    if (PASS == 0) {
        // channel sums -> replicated bins
        const int rep = (blockIdx.y * gridDim.x + blockIdx.x) & (NR - 1);
        float* b0 = bins + rep * 2 * C_OUT;
#pragma unroll
        for (int m = 0; m < 4; ++m) {
#pragma unroll
            for (int r = 0; r < 4; ++r) {
                float s1 = 0.f, s2 = 0.f;
#pragma unroll
                for (int nn = 0; nn < 4; ++nn) {
                    int tw = nn * 16 + l15;
                    float v = acc[m][nn][r];
                    if (tw < 50) { s1 += v; s2 += v * v; }
                }
#pragma unroll
                for (int off = 1; off < 16; off <<= 1) {
                    s1 += __shfl_xor(s1, off, 64);
                    s2 += __shfl_xor(s2, off, 64);
                }
                if (l15 == 0) {
                    int o = wbase + m * 16 + kg * 4 + r;
                    atomicAdd(&b0[o], s1);
                    atomicAdd(&b0[C_OUT + o], s2);
                }
            }
        }
    } else {
        // fused BN + ReLU write
        const size_t ybase = (size_t)nIdx * C_OUT * TW + (size_t)t0 * V_DIM;
#pragma unroll
        for (int m = 0; m < 4; ++m) {
#pragma unroll
            for (int r = 0; r < 4; ++r) {
                int o = wbase + m * 16 + kg * 4 + r;
                float2 sh = ssv[o];
                float* yp = y + ybase + (size_t)o * TW;
#pragma unroll
                for (int nn = 0; nn < 4; ++nn) {
                    int tw = nn * 16 + l15;
                    if (tw < 50)
                        yp[tw] = fmaxf(fmaf(acc[m][nn][r], sh.x, sh.y), 0.f);
                }
            }
        }
    }
}

// ---------------------------------------------------------------------------
// Reduce replica bins -> per-channel scale/shift
// ---------------------------------------------------------------------------
__global__ void k_stats(const float* __restrict__ bins, const float* __restrict__ bn_w,
                        const float* __restrict__ bn_b, float2* __restrict__ ssv, int n) {
    int o = threadIdx.x;   // 256
    float s1 = 0.f, s2 = 0.f;
    for (int rp = 0; rp < NR; ++rp) {
        s1 += bins[rp * 2 * C_OUT + o];
        s2 += bins[rp * 2 * C_OUT + C_OUT + o];
    }
    float cnt   = (float)n * (float)TW;
    float mean  = s1 / cnt;
    float var   = s2 / cnt - mean * mean;
    float scale = bn_w[o] * rsqrtf(var + BN_EPS);
    ssv[o] = make_float2(scale, bn_b[o] - mean * scale);
}

// ---------------------------------------------------------------------------
extern "C" void kernel_launch(void* const* d_in, const int* in_sizes, int n_in,
                              void* d_out, int out_size, void* d_ws, size_t ws_size,
                              hipStream_t stream) {
    const float* x      = (const float*)d_in[0];
    const float* A      = (const float*)d_in[1];
    const float* A_pers = (const float*)d_in[2];
    const float* conv_w = (const float*)d_in[3];
    // d_in[4] = conv_b: cancels under training-mode BatchNorm -> unused
    const float* bn_w   = (const float*)d_in[5];
    const float* bn_b   = (const float*)d_in[6];

    const int n = in_sizes[0] / (C_IN * TW);   // 64

    float* out_ap = (float*)d_out;
    float* y      = (float*)d_out + (size_t)n * AP_PER_N;

    // ws layout (16B aligned blocks)
    float*  bins = (float*)d_ws;                                   // NR*2*C_OUT floats (64 KB)
    float2* ssv  = (float2*)(bins + NR * 2 * C_OUT);               // C_OUT float2 (2 KB)
    unsigned short* afb  = (unsigned short*)((char*)(ssv + C_OUT));// n*6*64*8 bf16 (384 KB)
    unsigned short* wt_b = afb + (size_t)n * 6 * 64 * 8;           // C_OUT*SC bf16 (96 KB)

    hipMemsetAsync(bins, 0, NR * 2 * C_OUT * sizeof(float), stream);

    int totA = n * AP_PER_N;
    k_prep_a<<<(totA + 255) / 256, 256, 0, stream>>>(A_pers, out_ap, totA);
    int totF = n * 6 * 64 * 8;
    k_prep_afb<<<(totF + 255) / 256, 256, 0, stream>>>(A, A_pers, afb, totF);
    k_prep_w<<<(C_OUT * SC + 255) / 256, 256, 0, stream>>>(conv_w, wt_b);

    dim3 grid(T_DIM / 2, n);
    k_main<0><<<grid, 256, 0, stream>>>(x, afb, wt_b, y, bins, ssv);
    k_stats<<<1, 256, 0, stream>>>(bins, bn_w, bn_b, ssv, n);
    k_main<1><<<grid, 256, 0, stream>>>(x, afb, wt_b, y, bins, ssv);
}

// Round 4
// 424.940 us; speedup vs baseline: 3.3843x; 1.1165x over previous
//
#include <hip/hip_runtime.h>
#include <math.h>

#define C_IN   64
#define T_DIM  256
#define V_DIM  25
#define C_OUT  256
#define S_DIM  3
#define BN_EPS 1e-5f

#define SC       (S_DIM * C_IN)          // 192
#define TW       (T_DIM * V_DIM)         // 6400
#define AP_PER_N (S_DIM * V_DIM * V_DIM) // 1875
#define LDB      200                     // sXa row stride in bf16 (400 B): 16B-aligned rows, 8-lane/32-bank optimal for b128
#define LDX      32                      // sX row stride in bf16 (64 B)
#define NR       32                      // atomic replica count

typedef __attribute__((ext_vector_type(8))) short bf16x8;
typedef __attribute__((ext_vector_type(4))) float f32x4;

__device__ __forceinline__ unsigned short f2bf(float f) {
    unsigned u = __builtin_bit_cast(unsigned, f);
    unsigned r = u + 0x7fffu + ((u >> 16) & 1u);
    return (unsigned short)(r >> 16);
}

// ---------------------------------------------------------------------------
// A_personalized = tanh(A_pers[:n]) -> output 0
// ---------------------------------------------------------------------------
__global__ void k_prep_a(const float* __restrict__ A_pers, float* __restrict__ out_ap,
                         int total) {
    int i = blockIdx.x * 256 + threadIdx.x;
    if (i < total) out_ap[i] = tanhf(A_pers[i]);
}

// ---------------------------------------------------------------------------
// Pack A_final = A + tanh(A_pers) into exact MFMA B-fragment layout (bf16):
// afb[n][s][nt][lane][i] = Af[v = (lane>>4)*8+i][w = nt*16 + (lane&15)], 0-pad
// ---------------------------------------------------------------------------
__global__ void k_prep_afb(const float* __restrict__ A, const float* __restrict__ A_pers,
                           unsigned short* __restrict__ afb, int total) {
    int j = blockIdx.x * 256 + threadIdx.x;
    if (j >= total) return;
    int i    = j & 7;
    int lane = (j >> 3) & 63;
    int nt   = (j >> 9) & 1;
    int sn   = j >> 10;          // n*3 + s
    int s    = sn % 3;
    int n    = sn / 3;
    int v    = ((lane >> 4) << 3) + i;
    int w    = nt * 16 + (lane & 15);
    float val = 0.f;
    if (v < V_DIM && w < V_DIM)
        val = A[(s * V_DIM + v) * V_DIM + w] +
              tanhf(A_pers[((n * S_DIM + s) * V_DIM + v) * V_DIM + w]);
    afb[j] = f2bf(val);
}

// ---------------------------------------------------------------------------
// conv_w (S,C_OUT,C_IN) -> bf16 wt_b[o][sc], sc = s*64+c (stage-2 A-frag rows)
// ---------------------------------------------------------------------------
__global__ void k_prep_w(const float* __restrict__ conv_w, unsigned short* __restrict__ wt_b) {
    int j = blockIdx.x * 256 + threadIdx.x;    // C_OUT*SC = 49152
    if (j < C_OUT * SC) {
        int o  = j / SC;
        int sc = j - o * SC;
        int s  = sc >> 6, c = sc & 63;
        wt_b[j] = f2bf(conv_w[(s * C_OUT + o) * C_IN + c]);
    }
}

// ---------------------------------------------------------------------------
// Main: block = (t-pair, n). Stage1 MFMA: xa = X·Af -> sXa[tw][sc] (bf16).
// Stage2 MFMA: y[o][tw] = wt[o][sc] · xa[sc][tw].
// PASS 0: channel sums only (replicated atomic bins). PASS 1: BN+ReLU fused y write.
// ---------------------------------------------------------------------------
template <int PASS>
__global__ __launch_bounds__(256, 4) void k_main(const float* __restrict__ x,
                                                 const unsigned short* __restrict__ afb,
                                                 const unsigned short* __restrict__ wt_b,
                                                 float* __restrict__ y,
                                                 float* __restrict__ bins,
                                                 const float2* __restrict__ ssv) {
    __shared__ __align__(16) unsigned short sX[128 * LDX];   // 8 KB   [ct=2c+t][v pad 32]
    __shared__ __align__(16) unsigned short sXa[64 * LDB];   // 25.6 KB [tw][sc pad 200]

    const int tid  = threadIdx.x;
    const int nIdx = blockIdx.y;
    const int t0   = blockIdx.x * 2;
    const int lane = tid & 63;
    const int wv   = tid >> 6;     // wave 0..3
    const int l15  = lane & 15;
    const int kg   = lane >> 4;    // 0..3

    // Preload stage-1 B-fragments (afb, global, per-lane b128) — independent of LDS
    bf16x8 bS[6];
    {
        const unsigned short* afbN = afb + (size_t)nIdx * (6 * 64 * 8);
#pragma unroll
        for (int sq = 0; sq < 6; ++sq)
            bS[sq] = *(const bf16x8*)(afbN + (sq * 64 + lane) * 8);
    }

    // zero K-pad cols v=25..31 of sX: 512 tasks (1 short + 3 uints per row)
    for (int j = tid; j < 128 * 4; j += 256) {
        int row = j >> 2, p = j & 3;
        if (p == 0) sX[row * LDX + 25] = 0;
        else ((unsigned*)sX)[row * (LDX / 2) + 12 + p] = 0;   // cols 26-27,28-29,30-31
    }

    // stage x -> sX bf16, float2-vectorized (1600 float2 chunks)
    {
        const float* xb = x + (size_t)nIdx * C_IN * TW + (size_t)t0 * V_DIM;
        for (int q = tid; q < 1600; q += 256) {
            int c = q / 25, j = q - c * 25;
            float2 v2 = *(const float2*)(xb + (size_t)c * TW + 2 * j);
            unsigned short b0 = f2bf(v2.x), b1 = f2bf(v2.y);
            if (j < 12) {
                ((unsigned*)sX)[c * LDX + j] = (unsigned)b0 | ((unsigned)b1 << 16);
            } else if (j == 12) {
                sX[(2 * c) * LDX + 24] = b0;      // t=0, v=24
                sX[(2 * c + 1) * LDX]  = b1;      // t=1, v=0
            } else {
                int v = 2 * j - 25;               // odd, t=1
                sX[(2 * c + 1) * LDX + v]     = b0;
                sX[(2 * c + 1) * LDX + v + 1] = b1;
            }
        }
    }
    __syncthreads();

    // ---- stage 1: 12 MFMA per wave; paired-bf16 b32 LDS writes (2-way banks = free) ----
#pragma unroll
    for (int sq = 0; sq < 6; ++sq) {
        int s = sq >> 1, nt = sq & 1;
        int w = nt * 16 + l15;
#pragma unroll
        for (int m2 = 0; m2 < 2; ++m2) {
            int mt = wv * 2 + m2;
            bf16x8 aX = *(const bf16x8*)(sX + (mt * 16 + l15) * LDX + kg * 8);
            f32x4 c4 = __builtin_amdgcn_mfma_f32_16x16x32_bf16(
                aX, bS[sq], (f32x4){0.f, 0.f, 0.f, 0.f}, 0, 0, 0);
            if (w < V_DIM) {
                // c4[r]: ct = mt*16+kg*4+r -> (c = mt*8+kg*2 + (r>>1), t = r&1)
                unsigned u0 = (unsigned)f2bf(c4[0]) | ((unsigned)f2bf(c4[2]) << 16); // t=0
                unsigned u1 = (unsigned)f2bf(c4[1]) | ((unsigned)f2bf(c4[3]) << 16); // t=1
                unsigned col = s * 32 + mt * 4 + kg;     // dword column
                ((unsigned*)sXa)[w * (LDB / 2) + col]              = u0;
                ((unsigned*)sXa)[(V_DIM + w) * (LDB / 2) + col]    = u1;
            }
        }
    }
    __syncthreads();

    // ---- stage 2: M=256 (o), N=64 (tw, 50 valid), K=192; full unroll lets the
    //      scheduler hoist next-ks aF (L2) loads behind the MFMA cluster ----
    f32x4 acc[4][4];
#pragma unroll
    for (int m = 0; m < 4; ++m)
#pragma unroll
        for (int nn = 0; nn < 4; ++nn) acc[m][nn] = (f32x4){0.f, 0.f, 0.f, 0.f};

    const unsigned short* wrow = wt_b + (size_t)(wv * 64 + l15) * SC + kg * 8;
#pragma unroll
    for (int ks = 0; ks < 6; ++ks) {
        bf16x8 aF[4], bF[4];
#pragma unroll
        for (int m = 0; m < 4; ++m)
            aF[m] = *(const bf16x8*)(wrow + m * 16 * SC + ks * 32);
#pragma unroll
        for (int nn = 0; nn < 4; ++nn)
            bF[nn] = *(const bf16x8*)(sXa + (nn * 16 + l15) * LDB + ks * 32 + kg * 8);
#pragma unroll
        for (int m = 0; m < 4; ++m)
#pragma unroll
            for (int nn = 0; nn < 4; ++nn)
                acc[m][nn] = __builtin_amdgcn_mfma_f32_16x16x32_bf16(aF[m], bF[nn], acc[m][nn], 0, 0, 0);
    }

    const int wbase = wv * 64;
    if (PASS == 0) {
        // channel sums -> replicated bins
        const int rep = (blockIdx.y * gridDim.x + blockIdx.x) & (NR - 1);
        float* b0 = bins + rep * 2 * C_OUT;
#pragma unroll
        for (int m = 0; m < 4; ++m) {
#pragma unroll
            for (int r = 0; r < 4; ++r) {
                float s1, s2;
                {
                    float v0 = acc[m][0][r], v1 = acc[m][1][r], v2 = acc[m][2][r];
                    s1 = v0 + v1 + v2;
                    s2 = v0 * v0 + v1 * v1 + v2 * v2;
                    if (l15 < 2) {           // tw = 48+l15 < 50
                        float v3 = acc[m][3][r];
                        s1 += v3;
                        s2 += v3 * v3;
                    }
                }
#pragma unroll
                for (int off = 1; off < 16; off <<= 1) {
                    s1 += __shfl_xor(s1, off, 64);
                    s2 += __shfl_xor(s2, off, 64);
                }
                if (l15 == 0) {
                    int o = wbase + m * 16 + kg * 4 + r;
                    atomicAdd(&b0[o], s1);
                    atomicAdd(&b0[C_OUT + o], s2);
                }
            }
        }
    } else {
        // fused BN + ReLU write
        const size_t ybase = (size_t)nIdx * C_OUT * TW + (size_t)t0 * V_DIM;
        float2 sh[4][4];
#pragma unroll
        for (int m = 0; m < 4; ++m)
#pragma unroll
            for (int r = 0; r < 4; ++r)
                sh[m][r] = ssv[wbase + m * 16 + kg * 4 + r];
#pragma unroll
        for (int m = 0; m < 4; ++m) {
#pragma unroll
            for (int r = 0; r < 4; ++r) {
                int o = wbase + m * 16 + kg * 4 + r;
                float sc = sh[m][r].x, sf = sh[m][r].y;
                float* yp = y + ybase + (size_t)o * TW + l15;
                yp[0]  = fmaxf(fmaf(acc[m][0][r], sc, sf), 0.f);
                yp[16] = fmaxf(fmaf(acc[m][1][r], sc, sf), 0.f);
                yp[32] = fmaxf(fmaf(acc[m][2][r], sc, sf), 0.f);
                if (l15 < 2)
                    yp[48] = fmaxf(fmaf(acc[m][3][r], sc, sf), 0.f);
            }
        }
    }
}

// ---------------------------------------------------------------------------
// Reduce replica bins -> per-channel scale/shift
// ---------------------------------------------------------------------------
__global__ void k_stats(const float* __restrict__ bins, const float* __restrict__ bn_w,
                        const float* __restrict__ bn_b, float2* __restrict__ ssv, int n) {
    int o = threadIdx.x;   // 256
    float s1 = 0.f, s2 = 0.f;
    for (int rp = 0; rp < NR; ++rp) {
        s1 += bins[rp * 2 * C_OUT + o];
        s2 += bins[rp * 2 * C_OUT + C_OUT + o];
    }
    float cnt   = (float)n * (float)TW;
    float mean  = s1 / cnt;
    float var   = s2 / cnt - mean * mean;
    float scale = bn_w[o] * rsqrtf(var + BN_EPS);
    ssv[o] = make_float2(scale, bn_b[o] - mean * scale);
}

// ---------------------------------------------------------------------------
extern "C" void kernel_launch(void* const* d_in, const int* in_sizes, int n_in,
                              void* d_out, int out_size, void* d_ws, size_t ws_size,
                              hipStream_t stream) {
    const float* x      = (const float*)d_in[0];
    const float* A      = (const float*)d_in[1];
    const float* A_pers = (const float*)d_in[2];
    const float* conv_w = (const float*)d_in[3];
    // d_in[4] = conv_b: cancels under training-mode BatchNorm -> unused
    const float* bn_w   = (const float*)d_in[5];
    const float* bn_b   = (const float*)d_in[6];

    const int n = in_sizes[0] / (C_IN * TW);   // 64

    float* out_ap = (float*)d_out;
    float* y      = (float*)d_out + (size_t)n * AP_PER_N;

    // ws layout (16B aligned blocks)
    float*  bins = (float*)d_ws;                                   // NR*2*C_OUT floats (64 KB)
    float2* ssv  = (float2*)(bins + NR * 2 * C_OUT);               // C_OUT float2 (2 KB)
    unsigned short* afb  = (unsigned short*)((char*)(ssv + C_OUT));// n*6*64*8 bf16 (384 KB)
    unsigned short* wt_b = afb + (size_t)n * 6 * 64 * 8;           // C_OUT*SC bf16 (96 KB)

    hipMemsetAsync(bins, 0, NR * 2 * C_OUT * sizeof(float), stream);

    int totA = n * AP_PER_N;
    k_prep_a<<<(totA + 255) / 256, 256, 0, stream>>>(A_pers, out_ap, totA);
    int totF = n * 6 * 64 * 8;
    k_prep_afb<<<(totF + 255) / 256, 256, 0, stream>>>(A, A_pers, afb, totF);
    k_prep_w<<<(C_OUT * SC + 255) / 256, 256, 0, stream>>>(conv_w, wt_b);

    dim3 grid(T_DIM / 2, n);
    k_main<0><<<grid, 256, 0, stream>>>(x, afb, wt_b, y, bins, ssv);
    k_stats<<<1, 256, 0, stream>>>(bins, bn_w, bn_b, ssv, n);
    k_main<1><<<grid, 256, 0, stream>>>(x, afb, wt_b, y, bins, ssv);
}